// Round 7
// baseline (381.861 us; speedup 1.0000x reference)
//
#include <hip/hip_runtime.h>

typedef unsigned short u16;
typedef unsigned int u32;
typedef unsigned long long u64;
typedef __bf16 bf16x8 __attribute__((ext_vector_type(8)));
typedef float f32x4 __attribute__((ext_vector_type(4)));

#define S_LEN 4096
#define DM 256

__device__ __forceinline__ u16 f2b(float f) {
  u32 u = __builtin_bit_cast(u32, f);
  u = (u + 0x7FFFu + ((u >> 16) & 1u)) >> 16;
  return (u16)u;
}
__device__ __forceinline__ float b2f(u16 b) {
  return __builtin_bit_cast(float, (u32)b << 16);
}

__device__ __forceinline__ f32x4 mfma16(bf16x8 a, bf16x8 b, f32x4 c) {
  return __builtin_amdgcn_mfma_f32_16x16x32_bf16(a, b, c, 0, 0, 0);
}

// async 16B global->LDS (lane writes lds_base + lane*16)
__device__ __forceinline__ void gl_lds16(const u16* g, u16* l) {
  __builtin_amdgcn_global_load_lds(
      (const __attribute__((address_space(1))) u32*)g,
      (__attribute__((address_space(3))) u32*)l, 16, 0, 0);
}

#define SB() __builtin_amdgcn_sched_barrier(0)

// C[M][N] = (A[M][K] @ B[N][K]^T + bias) * scale   (NT gemm, K contiguous both sides)
template <int TIN_F32, int TOUT_F32, int BIAS_MODE>
__global__ __launch_bounds__(256, 2) void gemm_nt_kernel(
    const void* __restrict__ Ap, const void* __restrict__ Bp,
    void* __restrict__ Cp, const float* __restrict__ bias, float scale,
    int M, int N, int K, int lda, int ldb, int ldc,
    long sA, long sB, long sC) {
  __shared__ u16 As[64][72];
  __shared__ u16 Bs[64][72];
  const int tid = threadIdx.x;
  const int w = tid >> 6, ln = tid & 63, lg = ln >> 4, ll = ln & 15;
  const int m0 = blockIdx.x * 64, n0 = blockIdx.y * 64;
  const long zA = (long)blockIdx.z * sA, zB = (long)blockIdx.z * sB,
             zC = (long)blockIdx.z * sC;

  const f32x4 fzero = {0.f, 0.f, 0.f, 0.f};
  f32x4 acc[4];
#pragma unroll
  for (int i = 0; i < 4; ++i) acc[i] = fzero;

  const int srow = tid >> 2, scb = (tid & 3) * 16;
  const int nk = (K + 63) >> 6;
  for (int kc = 0; kc < nk; ++kc) {
    const int k0 = kc * 64;
    if (TIN_F32) {
      {
        const float* src = (const float*)Ap + zA + (size_t)(m0 + srow) * lda + k0 + scb;
        u16 t[16];
        if (k0 + 64 <= K) {
#pragma unroll
          for (int i = 0; i < 16; ++i) t[i] = f2b(src[i]);
        } else {
#pragma unroll
          for (int i = 0; i < 16; ++i) {
            int gk = k0 + scb + i;
            t[i] = (gk < K) ? f2b(src[i]) : (u16)0;
          }
        }
#pragma unroll
        for (int i = 0; i < 16; ++i) As[srow][scb + i] = t[i];
      }
      {
        const float* src = (const float*)Bp + zB + (size_t)(n0 + srow) * ldb + k0 + scb;
        u16 t[16];
        if (k0 + 64 <= K) {
#pragma unroll
          for (int i = 0; i < 16; ++i) t[i] = f2b(src[i]);
        } else {
#pragma unroll
          for (int i = 0; i < 16; ++i) {
            int gk = k0 + scb + i;
            t[i] = (gk < K) ? f2b(src[i]) : (u16)0;
          }
        }
#pragma unroll
        for (int i = 0; i < 16; ++i) Bs[srow][scb + i] = t[i];
      }
    } else {
      const u16* srcA = (const u16*)Ap + zA + (size_t)(m0 + srow) * lda + k0 + scb;
      *(bf16x8*)&As[srow][scb] = *(const bf16x8*)srcA;
      *(bf16x8*)&As[srow][scb + 8] = *(const bf16x8*)(srcA + 8);
      const u16* srcB = (const u16*)Bp + zB + (size_t)(n0 + srow) * ldb + k0 + scb;
      *(bf16x8*)&Bs[srow][scb] = *(const bf16x8*)srcB;
      *(bf16x8*)&Bs[srow][scb + 8] = *(const bf16x8*)(srcB + 8);
    }
    __syncthreads();
#pragma unroll
    for (int ks = 0; ks < 2; ++ks) {
      bf16x8 af = *(const bf16x8*)&As[w * 16 + ll][ks * 32 + lg * 8];
#pragma unroll
      for (int ct = 0; ct < 4; ++ct) {
        bf16x8 bfr = *(const bf16x8*)&Bs[ct * 16 + ll][ks * 32 + lg * 8];
        acc[ct] = mfma16(af, bfr, acc[ct]);
      }
    }
    __syncthreads();
  }

#pragma unroll
  for (int ct = 0; ct < 4; ++ct) {
#pragma unroll
    for (int j = 0; j < 4; ++j) {
      int row = m0 + w * 16 + lg * 4 + j;
      int col = n0 + ct * 16 + ll;
      float v = acc[ct][j];
      if (BIAS_MODE == 1) v += bias[col];
      if (BIAS_MODE == 2) v += bias[row];
      v *= scale;
      if (TOUT_F32)
        ((float*)Cp)[zC + (size_t)row * ldc + col] = v;
      else
        ((u16*)Cp)[zC + (size_t)row * ldc + col] = f2b(v);
    }
  }
}

// Wo_sum[d][e] = sum_h Wo[d][h*256+e]  (bf16)
__global__ void wos_kernel(const float* __restrict__ Wo, u16* __restrict__ WoS) {
  int d = blockIdx.x, e = threadIdx.x;
  const float* p = Wo + (size_t)d * 1024;
  WoS[(size_t)d * 256 + e] = f2b(p[e] + p[256 + e] + p[512 + e] + p[768 + e]);
}

// mask int32 -> bitmask (bit i of u64 group g of row r = mask[r][64g+i] != 0)
__global__ __launch_bounds__(256) void bitpack_kernel(const int* __restrict__ mask,
                                                      u32* __restrict__ mb) {
  const int ln = threadIdx.x & 63;
  const int gw = (int)((blockIdx.x * 256 + threadIdx.x) >> 6);
  const int nw = gridDim.x * 4;
  u64* mb64 = (u64*)mb;
  for (int it = gw; it < 131072; it += nw) {
    const int* p = mask + (size_t)it * 256 + ln;
    int v0 = p[0], v1 = p[64], v2 = p[128], v3 = p[192];
    u64 b0 = __ballot(v0 != 0);
    u64 b1 = __ballot(v1 != 0);
    u64 b2 = __ballot(v2 != 0);
    u64 b3 = __ballot(v3 != 0);
    if (ln < 4) {
      u64 val = ln == 0 ? b0 : (ln == 1 ? b1 : (ln == 2 ? b2 : b3));
      mb64[(size_t)it * 4 + ln] = val;
    }
  }
}

// Flash attention, no-max softmax, bitmask. SINGLE-buffered K and V LDS tiles
// (42.75KB total -> 3 blocks/CU = 12 waves/CU) with counted-vmcnt pipeline:
//   per tile FIFO: [K(t):4][mask(t):8][V(t):4]
//   top:     vmcnt(12) (K ready), barrier, QK, barrier
//   mid:     issue K(t+1) (cover = softmax+PV), vmcnt(4) (mask+V ready)
//   end:     softmax, PV, barrier, issue mask(t+1)+V(t+1) (cover = next QK)
// z=16 kv-chunks (ckv=256, 8 tiles) -> grid 1024, XCD-pinned 2 chunks/XCD.
__global__ __launch_bounds__(256, 3) void flash_kernel(
    const u16* __restrict__ qh, const u16* __restrict__ kh,
    const u16* __restrict__ vhT, const u32* __restrict__ mb,
    u16* __restrict__ Opart, float* __restrict__ Lpart,
    int ckv, int ntiles) {
  __shared__ u16 kh_s[32 * 256];  // 16KB, chunk swz: cc ^= row&7
  __shared__ u16 vs_s[256 * 32];  // 16KB, chunk swz: cc ^= (row>>1)&3
  __shared__ u16 p_s[4][32][40];  // 10KB per-wave P tile

  const int tid = threadIdx.x;
  const int w = tid >> 6, ln = tid & 63, lg = ln >> 4, ll = ln & 15;
  const int nwg = gridDim.x;
  const int wg = ((int)blockIdx.x & 7) * (nwg >> 3) + ((int)blockIdx.x >> 3);
  const int q0 = (wg & 31) * 128;
  const int b = (wg >> 5) & 1;
  const int h = wg >> 6;  // kv chunk

  bf16x8 qf[2][8];
#pragma unroll
  for (int qg = 0; qg < 2; ++qg) {
    const u16* qp = qh + (size_t)(b * S_LEN + q0 + w * 32 + qg * 16 + ll) * DM + lg * 8;
#pragma unroll
    for (int ks = 0; ks < 8; ++ks) qf[qg][ks] = *(const bf16x8*)(qp + ks * 32);
  }

  const f32x4 fzero = {0.f, 0.f, 0.f, 0.f};
  f32x4 acc_o[2][16];
#pragma unroll
  for (int qg = 0; qg < 2; ++qg)
#pragma unroll
    for (int i = 0; i < 16; ++i) acc_o[qg][i] = fzero;
  float l_run[2][4] = {{0.f, 0.f, 0.f, 0.f}, {0.f, 0.f, 0.f, 0.f}};

  const u16* kbase = kh + (size_t)(b * S_LEN + h * ckv) * DM;
  const u16* vbase = vhT + (size_t)b * DM * S_LEN + h * ckv;
  const u32* mbase = mb + (size_t)(b * S_LEN + q0 + w * 32) * 128 + (h * ckv >> 5);

  // 4 K-chunk DMAs per lane, pre-swizzled source, linear LDS dest
  auto stageK = [&](int t) {
#pragma unroll
    for (int i = 0; i < 4; ++i) {
      int c = i * 256 + tid;
      int row = c >> 5, ccl = c & 31;
      int ccg = ccl ^ (row & 7);
      gl_lds16(kbase + (size_t)(t * 32 + row) * DM + ccg * 8,
               &kh_s[(i * 256 + w * 64) * 8]);
    }
  };
  // 4 V-chunk DMAs per lane
  auto stageV = [&](int t) {
#pragma unroll
    for (int i = 0; i < 4; ++i) {
      int c = i * 256 + tid;
      int row = c >> 2, ccl = c & 3;
      int ccg = ccl ^ ((row >> 1) & 3);
      gl_lds16(vbase + (size_t)row * S_LEN + t * 32 + ccg * 8,
               &vs_s[(i * 256 + w * 64) * 8]);
    }
  };

  u32 mwc[2][4];
#define LOADMASK(t)                                                           \
  _Pragma("unroll") for (int qg = 0; qg < 2; ++qg)                            \
  _Pragma("unroll") for (int j = 0; j < 4; ++j)                               \
      mwc[qg][j] = mbase[(size_t)(qg * 16 + lg * 4 + j) * 128 + (t)];

#define QK_PHASE()                                                            \
  accs[0][0] = fzero; accs[0][1] = fzero;                                     \
  accs[1][0] = fzero; accs[1][1] = fzero;                                     \
  __builtin_amdgcn_s_setprio(1);                                              \
  _Pragma("unroll") for (int ks = 0; ks < 8; ++ks) {                          \
    _Pragma("unroll") for (int half = 0; half < 2; ++half) {                  \
      int krow = half * 16 + ll;                                              \
      bf16x8 kf = *(const bf16x8*)&kh_s[krow * 256 +                          \
                                        (((ks * 4 + lg) ^ (krow & 7)) << 3)]; \
      accs[0][half] = mfma16(qf[0][ks], kf, accs[0][half]);                   \
      accs[1][half] = mfma16(qf[1][ks], kf, accs[1][half]);                   \
    }                                                                         \
  }                                                                           \
  __builtin_amdgcn_s_setprio(0);

#define SM_PV_PHASE()                                                         \
  _Pragma("unroll") for (int qg = 0; qg < 2; ++qg) {                          \
    _Pragma("unroll") for (int j = 0; j < 4; ++j) {                           \
      u32 m = mwc[qg][j];                                                     \
      float p0 = ((m >> ll) & 1u) ? __expf(accs[qg][0][j]) : 0.f;             \
      float p1 = ((m >> (16 + ll)) & 1u) ? __expf(accs[qg][1][j]) : 0.f;      \
      l_run[qg][j] += p0 + p1;                                                \
      int r = qg * 16 + lg * 4 + j;                                           \
      p_s[w][r][ll] = f2b(p0);                                                \
      p_s[w][r][16 + ll] = f2b(p1);                                           \
    }                                                                         \
  }                                                                           \
  bf16x8 pf0 = *(const bf16x8*)&p_s[w][ll][lg * 8];                           \
  bf16x8 pf1 = *(const bf16x8*)&p_s[w][16 + ll][lg * 8];                      \
  __builtin_amdgcn_s_setprio(1);                                              \
  _Pragma("unroll") for (int dt = 0; dt < 16; ++dt) {                         \
    int vrow = dt * 16 + ll;                                                  \
    bf16x8 vf = *(const bf16x8*)&vs_s[vrow * 32 +                             \
                                      ((lg ^ ((vrow >> 1) & 3)) << 3)];       \
    acc_o[0][dt] = mfma16(pf0, vf, acc_o[0][dt]);                             \
    acc_o[1][dt] = mfma16(pf1, vf, acc_o[1][dt]);                             \
  }                                                                           \
  __builtin_amdgcn_s_setprio(0);

  // ---- prologue: FIFO [K(0):4, V(0):4, m(0):8] ----
  stageK(0);
  SB();
  stageV(0);
  SB();
  LOADMASK(0);
  SB();

  // ---- steady: t = 0 .. ntiles-2 ----
#pragma unroll 1
  for (int t = 0; t < ntiles - 1; ++t) {
    asm volatile("s_waitcnt vmcnt(12)" ::: "memory");  // K(t) resident
    SB();
    __builtin_amdgcn_s_barrier();
    SB();
    f32x4 accs[2][2];
    QK_PHASE();
    SB();
    __builtin_amdgcn_s_barrier();  // kh_s free
    SB();
    stageK(t + 1);  // cover = softmax+PV
    SB();
    asm volatile("s_waitcnt vmcnt(4)" ::: "memory");  // m(t)+V(t) resident
    SB();
    SM_PV_PHASE();
    SB();
    __builtin_amdgcn_s_barrier();  // vs_s free
    SB();
    LOADMASK(t + 1);  // cover = next QK
    SB();
    stageV(t + 1);
    SB();
  }

  // ---- last tile ----
  {
    asm volatile("s_waitcnt vmcnt(12)" ::: "memory");
    SB();
    __builtin_amdgcn_s_barrier();
    SB();
    f32x4 accs[2][2];
    QK_PHASE();
    SB();
    asm volatile("s_waitcnt vmcnt(0)" ::: "memory");  // m+V resident
    SB();
    SM_PV_PHASE();
  }

  // ---- epilogue: reduce l across 16 ll-lanes, write partials ----
#pragma unroll
  for (int qg = 0; qg < 2; ++qg) {
#pragma unroll
    for (int j = 0; j < 4; ++j) {
      float l = l_run[qg][j];
      l += __shfl_xor(l, 1);
      l += __shfl_xor(l, 2);
      l += __shfl_xor(l, 4);
      l += __shfl_xor(l, 8);
      l_run[qg][j] = l;
    }
  }
  const size_t growb = (size_t)h * 8192 + (size_t)b * S_LEN + q0 + w * 32;
  if (ll == 0) {
#pragma unroll
    for (int qg = 0; qg < 2; ++qg)
#pragma unroll
      for (int j = 0; j < 4; ++j)
        Lpart[growb + qg * 16 + lg * 4 + j] = l_run[qg][j];
  }
#pragma unroll
  for (int qg = 0; qg < 2; ++qg)
#pragma unroll
    for (int dt = 0; dt < 16; ++dt)
#pragma unroll
      for (int j = 0; j < 4; ++j)
        Opart[(growb + qg * 16 + lg * 4 + j) * 256 + dt * 16 + ll] =
            f2b(acc_o[qg][dt][j]);
}

// sum the nslots chunk partials, normalize, emit per_head bf16
__global__ void combine_kernel(const u16* __restrict__ Opart,
                               const float* __restrict__ Lpart,
                               u16* __restrict__ ph, int nslots) {
  const int r = blockIdx.x;
  const int d = threadIdx.x;
  float o = 0.f, l = 0.f;
  for (int s = 0; s < nslots; ++s) {
    l += Lpart[(size_t)s * 8192 + r];
    o += b2f(Opart[((size_t)s * 8192 + r) * 256 + d]);
  }
  ph[(size_t)r * 256 + d] = f2b(o / l);
}

extern "C" void kernel_launch(void* const* d_in, const int* in_sizes, int n_in,
                              void* d_out, int out_size, void* d_ws, size_t ws_size,
                              hipStream_t stream) {
  const float* q = (const float*)d_in[0];
  const float* k = (const float*)d_in[1];
  const float* v = (const float*)d_in[2];
  const int* mask = (const int*)d_in[3];
  const float* Wq = (const float*)d_in[4];
  const float* bq = (const float*)d_in[5];
  const float* Wk = (const float*)d_in[6];
  const float* bk = (const float*)d_in[7];
  const float* Wv = (const float*)d_in[8];
  const float* bv = (const float*)d_in[9];
  const float* Wo = (const float*)d_in[10];
  const float* bo = (const float*)d_in[11];

  char* ws = (char*)d_ws;
  u16* qh = (u16*)(ws + 0);              //  4 MiB [2][4096][256]; reused as ph
  u16* kh = (u16*)(ws + 4194304);        //  4 MiB [2][4096][256]
  u16* vhT = (u16*)(ws + 8388608);       //  4 MiB [2][256][4096] (transposed)
  u16* WoS = (u16*)(ws + 12582912);      //  128 KiB [256][256]
  u32* mb = (u32*)(ws + 12713984);       //  4 MiB bitmask [2][4096][128] u32
  u16* Op = (u16*)(ws + 16908288);       // [nslots][8192][256] bf16 partials
  // z=16 needs Op 64 MiB + Lp 512 KiB -> ws >= 84541440; else fall back z=8
  int nslots = (ws_size >= 84541440u) ? 16 : 8;
  float* Lp = (float*)(ws + 16908288 + (size_t)nslots * 8192 * 256 * 2);
  int ckv = S_LEN / nslots, ntiles = ckv / 32;

  dim3 blk(256);
  gemm_nt_kernel<1, 0, 1><<<dim3(128, 4, 1), blk, 0, stream>>>(
      q, Wq, qh, bq, 0.0625f, 8192, 256, 256, 256, 256, 256, 0, 0, 0);
  gemm_nt_kernel<1, 0, 1><<<dim3(128, 4, 1), blk, 0, stream>>>(
      k, Wk, kh, bk, 1.0f, 8192, 256, 264, 264, 264, 256, 0, 0, 0);
  gemm_nt_kernel<1, 0, 2><<<dim3(4, 64, 2), blk, 0, stream>>>(
      Wv, v, vhT, bv, 1.0f, 256, 4096, 256, 256, 256, 4096,
      0, (long)4096 * 256, (long)256 * 4096);
  wos_kernel<<<dim3(256), blk, 0, stream>>>(Wo, WoS);
  bitpack_kernel<<<dim3(2048), blk, 0, stream>>>(mask, mb);
  flash_kernel<<<dim3(64 * nslots), blk, 0, stream>>>(qh, kh, vhT, mb, Op, Lp,
                                                      ckv, ntiles);
  combine_kernel<<<dim3(8192), blk, 0, stream>>>(Op, Lp, qh, nslots);
  gemm_nt_kernel<0, 1, 1><<<dim3(128, 4, 1), blk, 0, stream>>>(
      qh, WoS, d_out, bo, 1.0f, 8192, 256, 256, 256, 256, 256, 0, 0, 0);
}

// Round 8
// 272.521 us; speedup vs baseline: 1.4012x; 1.4012x over previous
//
#include <hip/hip_runtime.h>

typedef unsigned short u16;
typedef unsigned int u32;
typedef unsigned long long u64;
typedef __bf16 bf16x8 __attribute__((ext_vector_type(8)));
typedef float f32x4 __attribute__((ext_vector_type(4)));

#define S_LEN 4096
#define DM 256

__device__ __forceinline__ u16 f2b(float f) {
  u32 u = __builtin_bit_cast(u32, f);
  u = (u + 0x7FFFu + ((u >> 16) & 1u)) >> 16;
  return (u16)u;
}
__device__ __forceinline__ float b2f(u16 b) {
  return __builtin_bit_cast(float, (u32)b << 16);
}

__device__ __forceinline__ f32x4 mfma16(bf16x8 a, bf16x8 b, f32x4 c) {
  return __builtin_amdgcn_mfma_f32_16x16x32_bf16(a, b, c, 0, 0, 0);
}

// async 16B global->LDS (lane writes lds_base + lane*16)
__device__ __forceinline__ void gl_lds16(const u16* g, u16* l) {
  __builtin_amdgcn_global_load_lds(
      (const __attribute__((address_space(1))) u32*)g,
      (__attribute__((address_space(3))) u32*)l, 16, 0, 0);
}

// C[M][N] = (A[M][K] @ B[N][K]^T + bias) * scale   (NT gemm, K contiguous both sides)
template <int TIN_F32, int TOUT_F32, int BIAS_MODE>
__global__ __launch_bounds__(256, 2) void gemm_nt_kernel(
    const void* __restrict__ Ap, const void* __restrict__ Bp,
    void* __restrict__ Cp, const float* __restrict__ bias, float scale,
    int M, int N, int K, int lda, int ldb, int ldc,
    long sA, long sB, long sC) {
  __shared__ u16 As[64][72];
  __shared__ u16 Bs[64][72];
  const int tid = threadIdx.x;
  const int w = tid >> 6, ln = tid & 63, lg = ln >> 4, ll = ln & 15;
  const int m0 = blockIdx.x * 64, n0 = blockIdx.y * 64;
  const long zA = (long)blockIdx.z * sA, zB = (long)blockIdx.z * sB,
             zC = (long)blockIdx.z * sC;

  const f32x4 fzero = {0.f, 0.f, 0.f, 0.f};
  f32x4 acc[4];
#pragma unroll
  for (int i = 0; i < 4; ++i) acc[i] = fzero;

  const int srow = tid >> 2, scb = (tid & 3) * 16;
  const int nk = (K + 63) >> 6;
  for (int kc = 0; kc < nk; ++kc) {
    const int k0 = kc * 64;
    if (TIN_F32) {
      {
        const float* src = (const float*)Ap + zA + (size_t)(m0 + srow) * lda + k0 + scb;
        u16 t[16];
        if (k0 + 64 <= K) {
#pragma unroll
          for (int i = 0; i < 16; ++i) t[i] = f2b(src[i]);
        } else {
#pragma unroll
          for (int i = 0; i < 16; ++i) {
            int gk = k0 + scb + i;
            t[i] = (gk < K) ? f2b(src[i]) : (u16)0;
          }
        }
#pragma unroll
        for (int i = 0; i < 16; ++i) As[srow][scb + i] = t[i];
      }
      {
        const float* src = (const float*)Bp + zB + (size_t)(n0 + srow) * ldb + k0 + scb;
        u16 t[16];
        if (k0 + 64 <= K) {
#pragma unroll
          for (int i = 0; i < 16; ++i) t[i] = f2b(src[i]);
        } else {
#pragma unroll
          for (int i = 0; i < 16; ++i) {
            int gk = k0 + scb + i;
            t[i] = (gk < K) ? f2b(src[i]) : (u16)0;
          }
        }
#pragma unroll
        for (int i = 0; i < 16; ++i) Bs[srow][scb + i] = t[i];
      }
    } else {
      const u16* srcA = (const u16*)Ap + zA + (size_t)(m0 + srow) * lda + k0 + scb;
      *(bf16x8*)&As[srow][scb] = *(const bf16x8*)srcA;
      *(bf16x8*)&As[srow][scb + 8] = *(const bf16x8*)(srcA + 8);
      const u16* srcB = (const u16*)Bp + zB + (size_t)(n0 + srow) * ldb + k0 + scb;
      *(bf16x8*)&Bs[srow][scb] = *(const bf16x8*)srcB;
      *(bf16x8*)&Bs[srow][scb + 8] = *(const bf16x8*)(srcB + 8);
    }
    __syncthreads();
#pragma unroll
    for (int ks = 0; ks < 2; ++ks) {
      bf16x8 af = *(const bf16x8*)&As[w * 16 + ll][ks * 32 + lg * 8];
#pragma unroll
      for (int ct = 0; ct < 4; ++ct) {
        bf16x8 bfr = *(const bf16x8*)&Bs[ct * 16 + ll][ks * 32 + lg * 8];
        acc[ct] = mfma16(af, bfr, acc[ct]);
      }
    }
    __syncthreads();
  }

#pragma unroll
  for (int ct = 0; ct < 4; ++ct) {
#pragma unroll
    for (int j = 0; j < 4; ++j) {
      int row = m0 + w * 16 + lg * 4 + j;
      int col = n0 + ct * 16 + ll;
      float v = acc[ct][j];
      if (BIAS_MODE == 1) v += bias[col];
      if (BIAS_MODE == 2) v += bias[row];
      v *= scale;
      if (TOUT_F32)
        ((float*)Cp)[zC + (size_t)row * ldc + col] = v;
      else
        ((u16*)Cp)[zC + (size_t)row * ldc + col] = f2b(v);
    }
  }
}

// Wo_sum[d][e] = sum_h Wo[d][h*256+e]  (bf16)
__global__ void wos_kernel(const float* __restrict__ Wo, u16* __restrict__ WoS) {
  int d = blockIdx.x, e = threadIdx.x;
  const float* p = Wo + (size_t)d * 1024;
  WoS[(size_t)d * 256 + e] = f2b(p[e] + p[256 + e] + p[512 + e] + p[768 + e]);
}

// mask int32 -> bitmask (bit i of u64 group g of row r = mask[r][64g+i] != 0)
__global__ __launch_bounds__(256) void bitpack_kernel(const int* __restrict__ mask,
                                                      u32* __restrict__ mb) {
  const int ln = threadIdx.x & 63;
  const int gw = (int)((blockIdx.x * 256 + threadIdx.x) >> 6);
  const int nw = gridDim.x * 4;
  u64* mb64 = (u64*)mb;
  for (int it = gw; it < 131072; it += nw) {
    const int* p = mask + (size_t)it * 256 + ln;
    int v0 = p[0], v1 = p[64], v2 = p[128], v3 = p[192];
    u64 b0 = __ballot(v0 != 0);
    u64 b1 = __ballot(v1 != 0);
    u64 b2 = __ballot(v2 != 0);
    u64 b3 = __ballot(v3 != 0);
    if (ln < 4) {
      u64 val = ln == 0 ? b0 : (ln == 1 ? b1 : (ln == 2 ? b2 : b3));
      mb64[(size_t)it * 4 + ln] = val;
    }
  }
}

// Flash attention, no-max softmax, bitmask, V direct from XCD-L2 (z=8 regime,
// proven near-compulsory traffic in R3/R6). Occupancy push: 64-q-row blocks
// (grid 1024 = 4 blocks/CU available), 4 waves x 16 q-rows, K double-buffered
// in LDS via global_load_lds (pre-swizzled source, linear dest). LDS 37.4KB ->
// 4 blocks/CU = 16 waves/CU. XCD i owns kv-chunk i (wg>>7 == XCD id).
__global__ __launch_bounds__(256, 4) void flash_kernel(
    const u16* __restrict__ qh, const u16* __restrict__ kh,
    const u16* __restrict__ vhT, const u32* __restrict__ mb,
    u16* __restrict__ Opart, float* __restrict__ Lpart) {
  __shared__ u16 kh_s[2][32 * 256];  // 32KB dbuf, chunk swz: cc ^= row&7
  __shared__ u16 p_s[4][16][40];     // 5KB per-wave P tile

  const int tid = threadIdx.x;
  const int w = tid >> 6, ln = tid & 63, lg = ln >> 4, ll = ln & 15;
  // grid 1024; XCD-swizzle: wg = (bid&7)*128 + bid>>3 -> h = wg>>7 = XCD id
  const int wg = ((int)blockIdx.x & 7) * 128 + ((int)blockIdx.x >> 3);
  const int q0 = (wg & 63) * 64;
  const int b = (wg >> 6) & 1;
  const int h = wg >> 7;  // kv chunk (512 each)

  bf16x8 qf[8];
  {
    const u16* qp = qh + (size_t)(b * S_LEN + q0 + w * 16 + ll) * DM + lg * 8;
#pragma unroll
    for (int ks = 0; ks < 8; ++ks) qf[ks] = *(const bf16x8*)(qp + ks * 32);
  }

  const f32x4 fzero = {0.f, 0.f, 0.f, 0.f};
  f32x4 acc_o[16];
#pragma unroll
  for (int i = 0; i < 16; ++i) acc_o[i] = fzero;
  float l_run[4] = {0.f, 0.f, 0.f, 0.f};

  const u16* kbase = kh + (size_t)(b * S_LEN + h * 512) * DM;
  const u16* vbase = vhT + (size_t)b * DM * S_LEN + h * 512;
  const u32* mbase = mb + (size_t)(b * S_LEN + q0 + w * 16) * 128 + h * 16;

  // K tile 32x256 = 1024 16B-chunks, 256 lanes x 4; pre-swizzled source,
  // linear LDS dest (chunk c -> lds offset c*16B).
  auto stage = [&](int t, int buf) {
#pragma unroll
    for (int i = 0; i < 4; ++i) {
      int c = i * 256 + tid;
      int row = c >> 5, ccl = c & 31;
      int ccg = ccl ^ (row & 7);
      gl_lds16(kbase + (size_t)(t * 32 + row) * DM + ccg * 8,
               &kh_s[buf][(i * 256 + w * 64) * 8]);
    }
  };

  stage(0, 0);
  __syncthreads();

  int cur = 0;
  for (int t = 0; t < 16; ++t) {
    // bitmask words (L2/L3-hot), consumed after QK
    u32 mw[4];
#pragma unroll
    for (int j = 0; j < 4; ++j)
      mw[j] = mbase[(size_t)(lg * 4 + j) * 128 + t];

    if (t + 1 < 16) stage(t + 1, cur ^ 1);

    f32x4 accs[2];
    accs[0] = fzero;
    accs[1] = fzero;
#pragma unroll
    for (int ks = 0; ks < 8; ++ks) {
#pragma unroll
      for (int half = 0; half < 2; ++half) {
        int krow = half * 16 + ll;
        bf16x8 kf = *(const bf16x8*)&kh_s[cur][krow * 256 +
                                              (((ks * 4 + lg) ^ (krow & 7)) << 3)];
        accs[half] = mfma16(qf[ks], kf, accs[half]);
      }
    }

#pragma unroll
    for (int j = 0; j < 4; ++j) {
      u32 m = mw[j];
      float p0 = ((m >> ll) & 1u) ? __expf(accs[0][j]) : 0.f;
      float p1 = ((m >> (16 + ll)) & 1u) ? __expf(accs[1][j]) : 0.f;
      l_run[j] += p0 + p1;
      int r = lg * 4 + j;
      p_s[w][r][ll] = f2b(p0);
      p_s[w][r][16 + ll] = f2b(p1);
    }
    bf16x8 pf = *(const bf16x8*)&p_s[w][ll][lg * 8];

#pragma unroll
    for (int dt = 0; dt < 16; ++dt) {
      const u16* vp = vbase + (size_t)(dt * 16 + ll) * S_LEN + t * 32 + lg * 8;
      bf16x8 vf = *(const bf16x8*)vp;
      acc_o[dt] = mfma16(pf, vf, acc_o[dt]);
    }
    __syncthreads();
    cur ^= 1;
  }

  // epilogue: reduce l across 16 ll-lanes, write partials
#pragma unroll
  for (int j = 0; j < 4; ++j) {
    float l = l_run[j];
    l += __shfl_xor(l, 1);
    l += __shfl_xor(l, 2);
    l += __shfl_xor(l, 4);
    l += __shfl_xor(l, 8);
    l_run[j] = l;
  }
  const size_t growb = (size_t)h * 8192 + (size_t)b * S_LEN + q0 + w * 16;
  if (ll == 0) {
#pragma unroll
    for (int j = 0; j < 4; ++j) Lpart[growb + lg * 4 + j] = l_run[j];
  }
#pragma unroll
  for (int dt = 0; dt < 16; ++dt)
#pragma unroll
    for (int j = 0; j < 4; ++j)
      Opart[(growb + lg * 4 + j) * 256 + dt * 16 + ll] = f2b(acc_o[dt][j]);
}

// sum the 8 chunk partials, normalize, emit per_head bf16
__global__ void combine_kernel(const u16* __restrict__ Opart,
                               const float* __restrict__ Lpart,
                               u16* __restrict__ ph) {
  const int r = blockIdx.x;
  const int d = threadIdx.x;
  float o = 0.f, l = 0.f;
#pragma unroll
  for (int s = 0; s < 8; ++s) {
    l += Lpart[(size_t)s * 8192 + r];
    o += b2f(Opart[((size_t)s * 8192 + r) * 256 + d]);
  }
  ph[(size_t)r * 256 + d] = f2b(o / l);
}

extern "C" void kernel_launch(void* const* d_in, const int* in_sizes, int n_in,
                              void* d_out, int out_size, void* d_ws, size_t ws_size,
                              hipStream_t stream) {
  const float* q = (const float*)d_in[0];
  const float* k = (const float*)d_in[1];
  const float* v = (const float*)d_in[2];
  const int* mask = (const int*)d_in[3];
  const float* Wq = (const float*)d_in[4];
  const float* bq = (const float*)d_in[5];
  const float* Wk = (const float*)d_in[6];
  const float* bk = (const float*)d_in[7];
  const float* Wv = (const float*)d_in[8];
  const float* bv = (const float*)d_in[9];
  const float* Wo = (const float*)d_in[10];
  const float* bo = (const float*)d_in[11];

  char* ws = (char*)d_ws;
  u16* qh = (u16*)(ws + 0);              //  4 MiB [2][4096][256]; reused as ph
  u16* kh = (u16*)(ws + 4194304);        //  4 MiB [2][4096][256]
  u16* vhT = (u16*)(ws + 8388608);       //  4 MiB [2][256][4096] (transposed)
  u16* WoS = (u16*)(ws + 12582912);      //  128 KiB [256][256]
  u32* mb = (u32*)(ws + 12713984);       //  4 MiB bitmask [2][4096][128] u32
  u16* Op = (u16*)(ws + 16908288);       // 32 MiB [8][8192][256] bf16 partials
  float* Lp = (float*)(ws + 50462720);   // 256 KiB [8][8192] f32 row sums

  dim3 blk(256);
  gemm_nt_kernel<1, 0, 1><<<dim3(128, 4, 1), blk, 0, stream>>>(
      q, Wq, qh, bq, 0.0625f, 8192, 256, 256, 256, 256, 256, 0, 0, 0);
  gemm_nt_kernel<1, 0, 1><<<dim3(128, 4, 1), blk, 0, stream>>>(
      k, Wk, kh, bk, 1.0f, 8192, 256, 264, 264, 264, 256, 0, 0, 0);
  gemm_nt_kernel<1, 0, 2><<<dim3(4, 64, 2), blk, 0, stream>>>(
      Wv, v, vhT, bv, 1.0f, 256, 4096, 256, 256, 256, 4096,
      0, (long)4096 * 256, (long)256 * 4096);
  wos_kernel<<<dim3(256), blk, 0, stream>>>(Wo, WoS);
  bitpack_kernel<<<dim3(2048), blk, 0, stream>>>(mask, mb);
  flash_kernel<<<dim3(1024), blk, 0, stream>>>(qh, kh, vhT, mb, Op, Lp);
  combine_kernel<<<dim3(8192), blk, 0, stream>>>(Op, Lp, qh);
  gemm_nt_kernel<0, 1, 1><<<dim3(128, 4, 1), blk, 0, stream>>>(
      qh, WoS, d_out, bo, 1.0f, 8192, 256, 256, 256, 256, 256, 0, 0, 0);
}

// Round 9
// 140.017 us; speedup vs baseline: 2.7272x; 1.9463x over previous
//
#include <hip/hip_runtime.h>

typedef unsigned short u16;
typedef unsigned int u32;
typedef unsigned long long u64;
typedef __bf16 bf16x8 __attribute__((ext_vector_type(8)));
typedef float f32x4 __attribute__((ext_vector_type(4)));
typedef u32 u32x4 __attribute__((ext_vector_type(4)));

#define S_LEN 4096
#define DM 256

__device__ __forceinline__ u16 f2b(float f) {
  u32 u = __builtin_bit_cast(u32, f);
  u = (u + 0x7FFFu + ((u >> 16) & 1u)) >> 16;
  return (u16)u;
}
__device__ __forceinline__ float b2f(u16 b) {
  return __builtin_bit_cast(float, (u32)b << 16);
}

__device__ __forceinline__ f32x4 mfma16(bf16x8 a, bf16x8 b, f32x4 c) {
  return __builtin_amdgcn_mfma_f32_16x16x32_bf16(a, b, c, 0, 0, 0);
}

// async 16B global->LDS (lane writes lds_base + lane*16)
__device__ __forceinline__ void gl_lds16(const u16* g, u16* l) {
  __builtin_amdgcn_global_load_lds(
      (const __attribute__((address_space(1))) u32*)g,
      (__attribute__((address_space(3))) u32*)l, 16, 0, 0);
}

// C[M][N] = (A[M][K] @ B[N][K]^T + bias) * scale   (NT gemm, K contiguous both sides)
template <int TIN_F32, int TOUT_F32, int BIAS_MODE>
__global__ __launch_bounds__(256, 2) void gemm_nt_kernel(
    const void* __restrict__ Ap, const void* __restrict__ Bp,
    void* __restrict__ Cp, const float* __restrict__ bias, float scale,
    int M, int N, int K, int lda, int ldb, int ldc,
    long sA, long sB, long sC) {
  __shared__ u16 As[64][72];
  __shared__ u16 Bs[64][72];
  const int tid = threadIdx.x;
  const int w = tid >> 6, ln = tid & 63, lg = ln >> 4, ll = ln & 15;
  const int m0 = blockIdx.x * 64, n0 = blockIdx.y * 64;
  const long zA = (long)blockIdx.z * sA, zB = (long)blockIdx.z * sB,
             zC = (long)blockIdx.z * sC;

  const f32x4 fzero = {0.f, 0.f, 0.f, 0.f};
  f32x4 acc[4];
#pragma unroll
  for (int i = 0; i < 4; ++i) acc[i] = fzero;

  const int srow = tid >> 2, scb = (tid & 3) * 16;
  const int nk = (K + 63) >> 6;
  for (int kc = 0; kc < nk; ++kc) {
    const int k0 = kc * 64;
    if (TIN_F32) {
      {
        const float* src = (const float*)Ap + zA + (size_t)(m0 + srow) * lda + k0 + scb;
        u16 t[16];
        if (k0 + 64 <= K) {
#pragma unroll
          for (int i = 0; i < 16; ++i) t[i] = f2b(src[i]);
        } else {
#pragma unroll
          for (int i = 0; i < 16; ++i) {
            int gk = k0 + scb + i;
            t[i] = (gk < K) ? f2b(src[i]) : (u16)0;
          }
        }
#pragma unroll
        for (int i = 0; i < 16; ++i) As[srow][scb + i] = t[i];
      }
      {
        const float* src = (const float*)Bp + zB + (size_t)(n0 + srow) * ldb + k0 + scb;
        u16 t[16];
        if (k0 + 64 <= K) {
#pragma unroll
          for (int i = 0; i < 16; ++i) t[i] = f2b(src[i]);
        } else {
#pragma unroll
          for (int i = 0; i < 16; ++i) {
            int gk = k0 + scb + i;
            t[i] = (gk < K) ? f2b(src[i]) : (u16)0;
          }
        }
#pragma unroll
        for (int i = 0; i < 16; ++i) Bs[srow][scb + i] = t[i];
      }
    } else {
      const u16* srcA = (const u16*)Ap + zA + (size_t)(m0 + srow) * lda + k0 + scb;
      *(bf16x8*)&As[srow][scb] = *(const bf16x8*)srcA;
      *(bf16x8*)&As[srow][scb + 8] = *(const bf16x8*)(srcA + 8);
      const u16* srcB = (const u16*)Bp + zB + (size_t)(n0 + srow) * ldb + k0 + scb;
      *(bf16x8*)&Bs[srow][scb] = *(const bf16x8*)srcB;
      *(bf16x8*)&Bs[srow][scb + 8] = *(const bf16x8*)(srcB + 8);
    }
    __syncthreads();
#pragma unroll
    for (int ks = 0; ks < 2; ++ks) {
      bf16x8 af = *(const bf16x8*)&As[w * 16 + ll][ks * 32 + lg * 8];
#pragma unroll
      for (int ct = 0; ct < 4; ++ct) {
        bf16x8 bfr = *(const bf16x8*)&Bs[ct * 16 + ll][ks * 32 + lg * 8];
        acc[ct] = mfma16(af, bfr, acc[ct]);
      }
    }
    __syncthreads();
  }

#pragma unroll
  for (int ct = 0; ct < 4; ++ct) {
#pragma unroll
    for (int j = 0; j < 4; ++j) {
      int row = m0 + w * 16 + lg * 4 + j;
      int col = n0 + ct * 16 + ll;
      float v = acc[ct][j];
      if (BIAS_MODE == 1) v += bias[col];
      if (BIAS_MODE == 2) v += bias[row];
      v *= scale;
      if (TOUT_F32)
        ((float*)Cp)[zC + (size_t)row * ldc + col] = v;
      else
        ((u16*)Cp)[zC + (size_t)row * ldc + col] = f2b(v);
    }
  }
}

// Wo_sum[d][e] = sum_h Wo[d][h*256+e]  (bf16)
__global__ void wos_kernel(const float* __restrict__ Wo, u16* __restrict__ WoS) {
  int d = blockIdx.x, e = threadIdx.x;
  const float* p = Wo + (size_t)d * 1024;
  WoS[(size_t)d * 256 + e] = f2b(p[e] + p[256 + e] + p[512 + e] + p[768 + e]);
}

// mask int32 -> bitmask (bit i of u64 group g of row r = mask[r][64g+i] != 0)
__global__ __launch_bounds__(256) void bitpack_kernel(const int* __restrict__ mask,
                                                      u32* __restrict__ mb) {
  const int ln = threadIdx.x & 63;
  const int gw = (int)((blockIdx.x * 256 + threadIdx.x) >> 6);
  const int nw = gridDim.x * 4;
  u64* mb64 = (u64*)mb;
  for (int it = gw; it < 131072; it += nw) {
    const int* p = mask + (size_t)it * 256 + ln;
    int v0 = p[0], v1 = p[64], v2 = p[128], v3 = p[192];
    u64 b0 = __ballot(v0 != 0);
    u64 b1 = __ballot(v1 != 0);
    u64 b2 = __ballot(v2 != 0);
    u64 b3 = __ballot(v3 != 0);
    if (ln < 4) {
      u64 val = ln == 0 ? b0 : (ln == 1 ? b1 : (ln == 2 ? b2 : b3));
      mb64[(size_t)it * 4 + ln] = val;
    }
  }
}

// Flash attention, no-max softmax, bitmask. R3 base (84.6us: K+V dbuf LDS via
// gl_lds, prefetch, __syncthreads loop, z=8, grid (32,2,8)) + two changes:
//  (1) swapped-QK in-register softmax: mfma(K,Q) puts 8 scores for q-row=ll
//      in-lane; mask via 2 bitmask words; cvt_pk -> 8-shfl redistribution to
//      the PV A-fragment layout. No p_s LDS roundtrip (LDS 74->64KB).
//  (2) V tile swizzled (src cc^=(row>>1)&3, matching XOR on PV read) to kill
//      the 8-way bank conflict of the linear [256][32] layout.
__global__ __launch_bounds__(256, 2) void flash_kernel(
    const u16* __restrict__ qh, const u16* __restrict__ kh,
    const u16* __restrict__ vhT, const u32* __restrict__ mb,
    u16* __restrict__ Opart, float* __restrict__ Lpart) {
  __shared__ u16 kh_s[2][32 * 256];  // 32KB dbuf, chunk swz: cc ^= row&7
  __shared__ u16 vs_s[2][256 * 32];  // 32KB dbuf, chunk swz: cc ^= (row>>1)&3

  const int tid = threadIdx.x;
  const int w = tid >> 6, ln = tid & 63, lg = ln >> 4, ll = ln & 15;
  const int q0 = blockIdx.x * 128;
  const int b = blockIdx.y;
  const int h = blockIdx.z;  // kv chunk (512 each)

  bf16x8 qf[2][8];
#pragma unroll
  for (int qg = 0; qg < 2; ++qg) {
    const u16* qp = qh + (size_t)(b * S_LEN + q0 + w * 32 + qg * 16 + ll) * DM + lg * 8;
#pragma unroll
    for (int ks = 0; ks < 8; ++ks) qf[qg][ks] = *(const bf16x8*)(qp + ks * 32);
  }

  const f32x4 fzero = {0.f, 0.f, 0.f, 0.f};
  f32x4 acc_o[2][16];
#pragma unroll
  for (int qg = 0; qg < 2; ++qg)
#pragma unroll
    for (int i = 0; i < 16; ++i) acc_o[qg][i] = fzero;
  float l_run[2] = {0.f, 0.f};

  const u16* kbase = kh + (size_t)(b * S_LEN + h * 512) * DM;
  const u16* vbase = vhT + (size_t)b * DM * S_LEN + h * 512;
  const u32* mbase = mb + (size_t)(b * S_LEN + q0 + w * 32) * 128 + h * 16;

  auto stage = [&](int t, int buf) {
#pragma unroll
    for (int i = 0; i < 4; ++i) {
      int c = i * 256 + tid;
      int row = c >> 5, ccl = c & 31;
      int ccg = ccl ^ (row & 7);  // pre-swizzled source, linear LDS dest
      gl_lds16(kbase + (size_t)(t * 32 + row) * DM + ccg * 8,
               &kh_s[buf][(i * 256 + w * 64) * 8]);
    }
#pragma unroll
    for (int i = 0; i < 4; ++i) {
      int c = i * 256 + tid;
      int row = c >> 2, ccl = c & 3;
      int ccg = ccl ^ ((row >> 1) & 3);
      gl_lds16(vbase + (size_t)row * S_LEN + t * 32 + ccg * 8,
               &vs_s[buf][(i * 256 + w * 64) * 8]);
    }
  };

  stage(0, 0);
  __syncthreads();

  int cur = 0;
  for (int t = 0; t < 16; ++t) {
    // bitmask words: q-row = ll (qg0) / 16+ll (qg1), tile word t
    u32 mw0 = mbase[(size_t)ll * 128 + t];
    u32 mw1 = mbase[(size_t)(16 + ll) * 128 + t];

    if (t + 1 < 16) stage(t + 1, cur ^ 1);

    // swapped QK: C[kv][q] -> lane holds scores for q=ll at
    // kv = half*16 + lg*4 + j
    f32x4 accs[2][2];
    accs[0][0] = fzero;
    accs[0][1] = fzero;
    accs[1][0] = fzero;
    accs[1][1] = fzero;
#pragma unroll
    for (int ks = 0; ks < 8; ++ks) {
#pragma unroll
      for (int half = 0; half < 2; ++half) {
        int krow = half * 16 + ll;
        bf16x8 kf = *(const bf16x8*)&kh_s[cur][krow * 256 +
                                              (((ks * 4 + lg) ^ (krow & 7)) << 3)];
        accs[0][half] = mfma16(kf, qf[0][ks], accs[0][half]);
        accs[1][half] = mfma16(kf, qf[1][ks], accs[1][half]);
      }
    }

    // in-register softmax + redistribution to PV A-fragment layout
    bf16x8 pf[2];
#pragma unroll
    for (int qg = 0; qg < 2; ++qg) {
      u32 m = qg ? mw1 : mw0;
      float p[2][4];
#pragma unroll
      for (int half = 0; half < 2; ++half)
#pragma unroll
        for (int j = 0; j < 4; ++j) {
          int bitpos = half * 16 + lg * 4 + j;
          float pv = ((m >> bitpos) & 1u) ? __expf(accs[qg][half][j]) : 0.f;
          p[half][j] = pv;
          l_run[qg] += pv;
        }
      u32 c0, c1, c2, c3;
      asm("v_cvt_pk_bf16_f32 %0, %1, %2" : "=v"(c0) : "v"(p[0][0]), "v"(p[0][1]));
      asm("v_cvt_pk_bf16_f32 %0, %1, %2" : "=v"(c1) : "v"(p[0][2]), "v"(p[0][3]));
      asm("v_cvt_pk_bf16_f32 %0, %1, %2" : "=v"(c2) : "v"(p[1][0]), "v"(p[1][1]));
      asm("v_cvt_pk_bf16_f32 %0, %1, %2" : "=v"(c3) : "v"(p[1][2]), "v"(p[1][3]));
      // target lane needs P[q=ll][kv=lg*8..+7]:
      //   words 0,1 from src lane sa = ll + 32*(lg&1)  (c0,c1 or c2,c3)
      //   words 2,3 from src lane sb = sa + 16
      int sa = ll + ((lg & 1) << 5);
      int sb = sa + 16;
      u32 t0 = (u32)__shfl((int)c0, sa), t1 = (u32)__shfl((int)c1, sa);
      u32 t2 = (u32)__shfl((int)c2, sa), t3 = (u32)__shfl((int)c3, sa);
      u32 u0 = (u32)__shfl((int)c0, sb), u1 = (u32)__shfl((int)c1, sb);
      u32 u2 = (u32)__shfl((int)c2, sb), u3 = (u32)__shfl((int)c3, sb);
      bool hi = (lg & 2) != 0;
      u32x4 pw;
      pw.x = hi ? t2 : t0;
      pw.y = hi ? t3 : t1;
      pw.z = hi ? u2 : u0;
      pw.w = hi ? u3 : u1;
      pf[qg] = __builtin_bit_cast(bf16x8, pw);
    }

#pragma unroll
    for (int dt = 0; dt < 16; ++dt) {
      int vrow = dt * 16 + ll;
      bf16x8 vf = *(const bf16x8*)&vs_s[cur][vrow * 32 +
                                            ((lg ^ ((vrow >> 1) & 3)) << 3)];
      acc_o[0][dt] = mfma16(pf[0], vf, acc_o[0][dt]);
      acc_o[1][dt] = mfma16(pf[1], vf, acc_o[1][dt]);
    }
    __syncthreads();
    cur ^= 1;
  }

  // epilogue: l_run[qg] holds 8-kv partial for q=ll; sum over the 4 lane
  // groups (xor 16, xor 32), then lane-group 0 writes.
  const size_t growb = (size_t)h * 8192 + (size_t)b * S_LEN + q0 + w * 32;
#pragma unroll
  for (int qg = 0; qg < 2; ++qg) {
    float l = l_run[qg];
    l += __shfl_xor(l, 16);
    l += __shfl_xor(l, 32);
    if (lg == 0) Lpart[growb + qg * 16 + ll] = l;
  }
#pragma unroll
  for (int qg = 0; qg < 2; ++qg)
#pragma unroll
    for (int dt = 0; dt < 16; ++dt)
#pragma unroll
      for (int j = 0; j < 4; ++j)
        Opart[(growb + qg * 16 + lg * 4 + j) * 256 + dt * 16 + ll] =
            f2b(acc_o[qg][dt][j]);
}

// sum the 8 chunk partials, normalize, emit per_head bf16
__global__ void combine_kernel(const u16* __restrict__ Opart,
                               const float* __restrict__ Lpart,
                               u16* __restrict__ ph) {
  const int r = blockIdx.x;
  const int d = threadIdx.x;
  float o = 0.f, l = 0.f;
#pragma unroll
  for (int s = 0; s < 8; ++s) {
    l += Lpart[(size_t)s * 8192 + r];
    o += b2f(Opart[((size_t)s * 8192 + r) * 256 + d]);
  }
  ph[(size_t)r * 256 + d] = f2b(o / l);
}

extern "C" void kernel_launch(void* const* d_in, const int* in_sizes, int n_in,
                              void* d_out, int out_size, void* d_ws, size_t ws_size,
                              hipStream_t stream) {
  const float* q = (const float*)d_in[0];
  const float* k = (const float*)d_in[1];
  const float* v = (const float*)d_in[2];
  const int* mask = (const int*)d_in[3];
  const float* Wq = (const float*)d_in[4];
  const float* bq = (const float*)d_in[5];
  const float* Wk = (const float*)d_in[6];
  const float* bk = (const float*)d_in[7];
  const float* Wv = (const float*)d_in[8];
  const float* bv = (const float*)d_in[9];
  const float* Wo = (const float*)d_in[10];
  const float* bo = (const float*)d_in[11];

  char* ws = (char*)d_ws;
  u16* qh = (u16*)(ws + 0);              //  4 MiB [2][4096][256]; reused as ph
  u16* kh = (u16*)(ws + 4194304);        //  4 MiB [2][4096][256]
  u16* vhT = (u16*)(ws + 8388608);       //  4 MiB [2][256][4096] (transposed)
  u16* WoS = (u16*)(ws + 12582912);      //  128 KiB [256][256]
  u32* mb = (u32*)(ws + 12713984);       //  4 MiB bitmask [2][4096][128] u32
  u16* Op = (u16*)(ws + 16908288);       // 32 MiB [8][8192][256] bf16 partials
  float* Lp = (float*)(ws + 50462720);   // 256 KiB [8][8192] f32 row sums

  dim3 blk(256);
  gemm_nt_kernel<1, 0, 1><<<dim3(128, 4, 1), blk, 0, stream>>>(
      q, Wq, qh, bq, 0.0625f, 8192, 256, 256, 256, 256, 256, 0, 0, 0);
  gemm_nt_kernel<1, 0, 1><<<dim3(128, 4, 1), blk, 0, stream>>>(
      k, Wk, kh, bk, 1.0f, 8192, 256, 264, 264, 264, 256, 0, 0, 0);
  gemm_nt_kernel<1, 0, 2><<<dim3(4, 64, 2), blk, 0, stream>>>(
      Wv, v, vhT, bv, 1.0f, 256, 4096, 256, 256, 256, 4096,
      0, (long)4096 * 256, (long)256 * 4096);
  wos_kernel<<<dim3(256), blk, 0, stream>>>(Wo, WoS);
  bitpack_kernel<<<dim3(2048), blk, 0, stream>>>(mask, mb);
  flash_kernel<<<dim3(32, 2, 8), blk, 0, stream>>>(qh, kh, vhT, mb, Op, Lp);
  combine_kernel<<<dim3(8192), blk, 0, stream>>>(Op, Lp, qh);
  gemm_nt_kernel<0, 1, 1><<<dim3(128, 4, 1), blk, 0, stream>>>(
      qh, WoS, d_out, bo, 1.0f, 8192, 256, 256, 256, 256, 256, 0, 0, 0);
}